// Round 13
// baseline (1917.208 us; speedup 1.0000x reference)
//
#include <hip/hip_runtime.h>
#include <stdint.h>

#define NN 50000
#define NE 1600000
#define FIN 128
#define FOUT 64
#define NR 4
#define ROWS 32
#define BSH 6
#define NB 782            // ceil(NN/64) buckets of 64 dsts
#define CAP 4096          // bucket capacity (mean 2048, Poisson, >40 sigma)
#define CB 128            // stream blocks for count/bin
#define EPB 12500         // NE / CB exactly
#define GEMM_BLOCKS 1563  // ceil(NN/ROWS)
#define AGG2_BLOCKS 2048  // 8192 waves, ALL resident -> lockstep chunk passes
#define NCHUNK 7          // src chunks of 8192 nodes (2 MB pk slice, L2-fit)
#define DPW 7             // dsts per wave: 7*8192 >= 50000

__device__ __forceinline__ uint32_t f2bf(float f) {   // RNE to bf16 bits
    uint32_t u = __float_as_uint(f);
    u += 0x7FFFu + ((u >> 16) & 1u);
    return u >> 16;
}

// ---------------- init: inverse perm + zero summaries -------------------------
__global__ __launch_bounds__(256) void init_k(const int* __restrict__ perm,
                                              int* __restrict__ invp,
                                              float* __restrict__ summ)
{
    int i = blockIdx.x * 256 + threadIdx.x;
    int r = blockIdx.y;
    if (i < NN) invp[r * NN + perm[r * NN + i]] = i;
    if (r == 0 && blockIdx.x == 0 && i < NR * FOUT) summ[i] = 0.0f;
}

// ---------------- pass 1: per-(block,bucket) histogram (LDS atomics only) -----
__global__ __launch_bounds__(256) void cnt_k(const int* __restrict__ eid,
                                             int* __restrict__ counts)
{
    __shared__ int hist[NB];
    for (int j = threadIdx.x; j < NB; j += 256) hist[j] = 0;
    __syncthreads();
    const int base = blockIdx.x * EPB;
    for (int t = threadIdx.x; t < EPB; t += 256)
        atomicAdd(&hist[eid[base + t] >> BSH], 1);
    __syncthreads();
    for (int j = threadIdx.x; j < NB; j += 256)
        counts[blockIdx.x * NB + j] = hist[j];
}

// ---------------- pass 2: per-bucket exclusive scan over the 128 blocks -------
__global__ __launch_bounds__(128) void scan_k(const int* __restrict__ counts,
                                              int* __restrict__ bases,
                                              int* __restrict__ bcnt)
{
    const int b = blockIdx.x, t = threadIdx.x;
    __shared__ int sc[CB];
    int v = counts[t * NB + b];
    sc[t] = v;
    __syncthreads();
    for (int off = 1; off < CB; off <<= 1) {
        int u = (t >= off) ? sc[t - off] : 0;
        __syncthreads();
        sc[t] += u;
        __syncthreads();
    }
    bases[t * NB + b] = b * CAP + (sc[t] - v);
    if (t == CB - 1) bcnt[b] = sc[t];
}

// ---------------- pass 3: scatter into bucket runs (LDS cursors) --------------
__global__ __launch_bounds__(256) void bin_k(const int* __restrict__ ei,
                                             const int* __restrict__ bases,
                                             uint32_t* __restrict__ recs)
{
    __shared__ int cur[NB];
    for (int j = threadIdx.x; j < NB; j += 256)
        cur[j] = bases[blockIdx.x * NB + j];
    __syncthreads();
    const int base = blockIdx.x * EPB;
    for (int t = threadIdx.x; t < EPB; t += 256) {
        int e = base + t;
        int src = ei[e];
        int dst = ei[NE + e];
        int bkt = dst >> BSH;
        int idx = atomicAdd(&cur[bkt], 1);
        if (idx < (bkt + 1) * CAP)
            recs[idx] = ((uint32_t)(dst & 63) << 16) | (uint32_t)src;
    }
}

// ---------------- pass 4: per-bucket counting sort by dst ---------------------
// emits per-dst contiguous (8-aligned) u16 src runs + dpack = {deg<<24 | start}
__global__ __launch_bounds__(256) void sort_k(const uint32_t* __restrict__ recs,
                                              const int* __restrict__ bcnt,
                                              uint16_t* __restrict__ srt,
                                              uint32_t* __restrict__ dpack)
{
    __shared__ uint32_t sr[CAP];      // 16 KB
    __shared__ int cnt4[4][64];
    __shared__ int start64[64];
    __shared__ int cur4[4][64];
    const int b = blockIdx.x, t = threadIdx.x, w = t >> 6;
    const int n = min(bcnt[b], CAP);

    for (int j = t; j < n; j += 256) sr[j] = recs[(size_t)b * CAP + j];
    cnt4[t >> 6][t & 63] = 0;
    __syncthreads();

    for (int j = t; j < n; j += 256)
        atomicAdd(&cnt4[w][sr[j] >> 16], 1);
    __syncthreads();

    if (t == 0) {
        int acc = 0;
        #pragma unroll 8
        for (int dl = 0; dl < 64; ++dl) {
            int tot = cnt4[0][dl] + cnt4[1][dl] + cnt4[2][dl] + cnt4[3][dl];
            start64[dl] = acc;
            acc += (tot + 7) & ~7;               // 8-pad each run (uint4 loads)
        }
    }
    __syncthreads();

    if (t < 64) {
        int s = start64[t];
        int c0 = cnt4[0][t], c1 = cnt4[1][t], c2 = cnt4[2][t];
        cur4[0][t] = s;
        cur4[1][t] = s + c0;
        cur4[2][t] = s + c0 + c1;
        cur4[3][t] = s + c0 + c1 + c2;
        int dst = b * 64 + t;
        if (dst < NN) {
            int tot = c0 + c1 + c2 + cnt4[3][t];
            dpack[dst] = ((uint32_t)min(tot, 255) << 24) |
                         (uint32_t)(b * CAP + s);
        }
    }
    __syncthreads();

    for (int j = t; j < n; j += 256) {
        uint32_t r = sr[j];
        int dl = r >> 16;
        int idx = atomicAdd(&cur4[w][dl], 1);
        if (idx < CAP) srt[(size_t)b * CAP + idx] = (uint16_t)(r & 0xFFFF);
    }
}

// ---------------- gemm: pos/neg masked GEMM -> SCALED packed bf16 table -------
__global__ __launch_bounds__(256) void gemm_k(const float* __restrict__ x,
                                              const float* __restrict__ pm,
                                              const float* __restrict__ nm,
                                              const float* __restrict__ Wr,
                                              const uint32_t* __restrict__ dpack,
                                              const int*   __restrict__ invp_r,
                                              uint32_t* __restrict__ pk)
{
    __shared__ float sW[FIN * FOUT];      // 32 KB
    __shared__ float sAp[ROWS * FIN];     // 16 KB (XOR-swizzled)
    __shared__ float sAn[ROWS * FIN];     // 16 KB
    const int t = threadIdx.x;
    const int row0 = blockIdx.x * ROWS;

    for (int i = t * 4; i < FIN * FOUT; i += 1024)
        *(float4*)&sW[i] = *(const float4*)&Wr[i];

    for (int i = t * 4; i < ROWS * FIN; i += 1024) {
        int rr = i >> 7, cc = i & 127;
        int row = row0 + rr;
        float4 ap = make_float4(0.f, 0.f, 0.f, 0.f), an = ap;
        if (row < NN) {
            size_t g = (size_t)row * FIN + cc;
            float4 xv = *(const float4*)(x + g);
            float4 pv = *(const float4*)(pm + g);
            float4 nv = *(const float4*)(nm + g);
            ap = make_float4(xv.x * pv.x, xv.y * pv.y, xv.z * pv.z, xv.w * pv.w);
            an = make_float4(xv.x * nv.x, xv.y * nv.y, xv.z * nv.z, xv.w * nv.w);
        }
        int sidx = (rr << 7) + (cc ^ ((rr & 7) << 2));
        *(float4*)&sAp[sidx] = ap;
        *(float4*)&sAn[sidx] = an;
    }
    __syncthreads();

    const int tr = (t >> 4) * 2;
    const int tc = (t & 15) * 4;
    float accp[2][4] = {{0.f,0.f,0.f,0.f},{0.f,0.f,0.f,0.f}};
    float accn[2][4] = {{0.f,0.f,0.f,0.f},{0.f,0.f,0.f,0.f}};

    #pragma unroll 4
    for (int k = 0; k < FIN; k += 4) {
        float4 p0 = *(const float4*)&sAp[((tr    ) << 7) + (k ^ (((tr    ) & 7) << 2))];
        float4 p1 = *(const float4*)&sAp[((tr + 1) << 7) + (k ^ (((tr + 1) & 7) << 2))];
        float4 n0 = *(const float4*)&sAn[((tr    ) << 7) + (k ^ (((tr    ) & 7) << 2))];
        float4 n1 = *(const float4*)&sAn[((tr + 1) << 7) + (k ^ (((tr + 1) & 7) << 2))];
        float ap0[4] = {p0.x, p0.y, p0.z, p0.w};
        float ap1[4] = {p1.x, p1.y, p1.z, p1.w};
        float an0[4] = {n0.x, n0.y, n0.z, n0.w};
        float an1[4] = {n1.x, n1.y, n1.z, n1.w};
        #pragma unroll
        for (int j = 0; j < 4; ++j) {
            float4 wv = *(const float4*)&sW[(k + j) * FOUT + tc];
            float wj[4] = {wv.x, wv.y, wv.z, wv.w};
            #pragma unroll
            for (int c = 0; c < 4; ++c) {
                accp[0][c] += ap0[j] * wj[c];
                accp[1][c] += ap1[j] * wj[c];
                accn[0][c] += an0[j] * wj[c];
                accn[1][c] += an1[j] * wj[c];
            }
        }
    }

    #pragma unroll
    for (int rr = 0; rr < 2; ++rr) {
        int row = row0 + tr + rr;
        if (row >= NN) continue;
        float dp = rsqrtf((float)(dpack[row] >> 24) + 1.0f);
        int ni = invp_r[row];
        float dn = rsqrtf((float)(dpack[ni] >> 24) + 1.0f);
        #pragma unroll
        for (int c = 0; c < 4; ++c) {
            ((uint16_t*)&pk[(size_t)row * 64 + tc + c])[1] = (uint16_t)f2bf(accp[rr][c] * dp);
            ((uint16_t*)&pk[(size_t)ni  * 64 + tc + c])[0] = (uint16_t)f2bf(accn[rr][c] * dn);
        }
    }
}

// ---------------- agg2: src-chunked multi-pass, register-resident acc ---------
// 8192 waves all resident; pass p gathers only srcs in chunk p (2 MB pk slice,
// L2-resident). Each wave owns DPW dsts; acc in registers across passes.
__global__ __launch_bounds__(256) void agg2_k(const uint32_t* __restrict__ dpack,
                                              const uint16_t* __restrict__ srt,
                                              const uint32_t* __restrict__ pk,
                                              const float* __restrict__ br,
                                              float* __restrict__ outp,
                                              float* __restrict__ outn,
                                              float* __restrict__ summ)
{
    const int lane = threadIdx.x & 63;
    const int w0 = blockIdx.x * 4 + (threadIdx.x >> 6);   // 0..8191
    const float bl = br[lane];

    float accp[DPW], accn[DPW];
    #pragma unroll
    for (int it = 0; it < DPW; ++it) { accp[it] = 0.f; accn[it] = 0.f; }

    for (int p = 0; p < NCHUNK; ++p) {
        #pragma unroll
        for (int it = 0; it < DPW; ++it) {
            int dst = w0 + it * 8192;
            if (dst >= NN) continue;
            uint32_t pc = dpack[dst];
            int deg = (int)(pc >> 24);
            const uint16_t* row = srt + (pc & 0xFFFFFFu);
            float ap = accp[it], an = accn[it];
            if ((dst >> 13) == p) {                       // self-loop in its chunk
                uint32_t gs = pk[(size_t)dst * 64 + lane];
                ap += __uint_as_float(gs & 0xFFFF0000u);
                an += __uint_as_float(gs << 16);
            }
            int j = 0;
            for (; j + 8 <= deg; j += 8) {
                uint4 rv = *(const uint4*)(row + j);      // wave-uniform 16B
                int s[8] = { (int)(rv.x & 0xFFFF), (int)(rv.x >> 16),
                             (int)(rv.y & 0xFFFF), (int)(rv.y >> 16),
                             (int)(rv.z & 0xFFFF), (int)(rv.z >> 16),
                             (int)(rv.w & 0xFFFF), (int)(rv.w >> 16) };
                #pragma unroll
                for (int u = 0; u < 8; ++u) {
                    if ((s[u] >> 13) == p) {              // wave-uniform branch
                        uint32_t g = pk[(size_t)s[u] * 64 + lane];
                        ap += __uint_as_float(g & 0xFFFF0000u);
                        an += __uint_as_float(g << 16);
                    }
                }
            }
            for (; j < deg; ++j) {
                int sv = row[j];
                if ((sv >> 13) == p) {
                    uint32_t g = pk[(size_t)sv * 64 + lane];
                    ap += __uint_as_float(g & 0xFFFF0000u);
                    an += __uint_as_float(g << 16);
                }
            }
            accp[it] = ap; accn[it] = an;
        }
    }

    float part = 0.f;
    #pragma unroll
    for (int it = 0; it < DPW; ++it) {
        int dst = w0 + it * 8192;
        if (dst >= NN) continue;
        int deg = (int)(dpack[dst] >> 24);
        float d = rsqrtf((float)deg + 1.0f);
        float op = fmaxf(fmaf(d, accp[it], bl), 0.f);
        float on = fmaxf(fmaf(d, accn[it], bl), 0.f);
        outp[(size_t)dst * FOUT + lane] = op;
        outn[(size_t)dst * FOUT + lane] = on;
        part += op;
    }

    __shared__ float red[256];
    red[threadIdx.x] = part;
    __syncthreads();
    if (threadIdx.x < 64) {
        float s = red[threadIdx.x] + red[threadIdx.x + 64] +
                  red[threadIdx.x + 128] + red[threadIdx.x + 192];
        atomicAdd(&summ[threadIdx.x], s * (1.0f / NN));
    }
}

extern "C" void kernel_launch(void* const* d_in, const int* in_sizes, int n_in,
                              void* d_out, int out_size, void* d_ws, size_t ws_size,
                              hipStream_t stream)
{
    const float* x    = (const float*)d_in[0];
    const int*   ei   = (const int*)  d_in[1];
    const float* W    = (const float*)d_in[2];
    const float* b    = (const float*)d_in[3];
    const float* pm   = (const float*)d_in[4];
    const float* nm   = (const float*)d_in[5];
    const int*   perm = (const int*)  d_in[6];
    float* out = (float*)d_out;

    // ws: invp[R*N] | counts[CB*NB] | bases[CB*NB] | bcnt[800 pad] | recs[NB*CAP] u32
    //   | srt[NB*CAP] u16 | dpack[NN] u32 | pk[NN*64] u32          (~34 MB)
    int*      invp   = (int*)d_ws;
    int*      counts = invp + (size_t)NR * NN;
    int*      bases  = counts + (size_t)CB * NB;
    int*      bcnt   = bases + (size_t)CB * NB;
    uint32_t* recs   = (uint32_t*)(bcnt + 800);
    uint16_t* srt    = (uint16_t*)(recs + (size_t)NB * CAP);
    uint32_t* dpack  = (uint32_t*)(srt + (size_t)NB * CAP);
    uint32_t* pk     = dpack + NN;

    const size_t NF = (size_t)NN * FOUT;
    float* outp0 = out;
    float* outn0 = out + (size_t)NR * NF;
    float* summ  = out + 2 * (size_t)NR * NF;

    init_k<<<dim3((NN + 255) / 256, NR), 256, 0, stream>>>(perm, invp, summ);

    for (int r = 0; r < NR; ++r) {
        const int* ei_r = ei + (size_t)r * 2 * NE;
        cnt_k <<<dim3(CB), 256, 0, stream>>>(ei_r + NE, counts);
        scan_k<<<dim3(NB), 128, 0, stream>>>(counts, bases, bcnt);
        bin_k <<<dim3(CB), 256, 0, stream>>>(ei_r, bases, recs);
        sort_k<<<dim3(NB), 256, 0, stream>>>(recs, bcnt, srt, dpack);
        gemm_k<<<dim3(GEMM_BLOCKS), 256, 0, stream>>>(
            x, pm + (size_t)r * NN * FIN, nm + (size_t)r * NN * FIN,
            W + (size_t)r * FIN * FOUT, dpack, invp + (size_t)r * NN, pk);
        agg2_k<<<dim3(AGG2_BLOCKS), 256, 0, stream>>>(
            dpack, srt, pk, b + (size_t)r * FOUT,
            outp0 + r * NF, outn0 + r * NF, summ + r * FOUT);
    }
}

// Round 14
// 943.825 us; speedup vs baseline: 2.0313x; 2.0313x over previous
//
#include <hip/hip_runtime.h>
#include <stdint.h>

#define NN 50000
#define NE 1600000
#define FIN 128
#define FOUT 64
#define NR 4
#define ROWS 32
#define BSH 6
#define NB 782            // ceil(NN/64) buckets of 64 dsts
#define CAP 4096          // bucket capacity (mean 2048, Poisson, >40 sigma)
#define CB 128            // stream blocks for count/bin
#define EPB 12500         // NE / CB exactly
#define GEMM_BLOCKS 1563  // ceil(NN/ROWS)
#define AGG_BLOCKS 3125   // x4 waves = 12500 waves, one dst per wave
#define FUSE_BLOCKS (GEMM_BLOCKS * 3)   // role = blockIdx%3: 0 gemm, 1-2 agg

__device__ __forceinline__ uint32_t f2bf(float f) {   // RNE to bf16 bits
    uint32_t u = __float_as_uint(f);
    u += 0x7FFFu + ((u >> 16) & 1u);
    return u >> 16;
}

// ---------------- init: inverse perm + zero summaries -------------------------
__global__ __launch_bounds__(256) void init_k(const int* __restrict__ perm,
                                              int* __restrict__ invp,
                                              float* __restrict__ summ)
{
    int i = blockIdx.x * 256 + threadIdx.x;
    int r = blockIdx.y;
    if (i < NN) invp[r * NN + perm[r * NN + i]] = i;
    if (r == 0 && blockIdx.x == 0 && i < NR * FOUT) summ[i] = 0.0f;
}

// ---------------- pass 1: per-(block,bucket) histogram (LDS atomics only) -----
__global__ __launch_bounds__(256) void cnt_k(const int* __restrict__ eid,
                                             int* __restrict__ counts)
{
    __shared__ int hist[NB];
    for (int j = threadIdx.x; j < NB; j += 256) hist[j] = 0;
    __syncthreads();
    const int base = blockIdx.x * EPB;
    for (int t = threadIdx.x; t < EPB; t += 256)
        atomicAdd(&hist[eid[base + t] >> BSH], 1);
    __syncthreads();
    for (int j = threadIdx.x; j < NB; j += 256)
        counts[blockIdx.x * NB + j] = hist[j];
}

// ---------------- pass 2: per-bucket exclusive scan over the 128 blocks -------
__global__ __launch_bounds__(128) void scan_k(const int* __restrict__ counts,
                                              int* __restrict__ bases,
                                              int* __restrict__ bcnt)
{
    const int b = blockIdx.x, t = threadIdx.x;
    __shared__ int sc[CB];
    int v = counts[t * NB + b];
    sc[t] = v;
    __syncthreads();
    for (int off = 1; off < CB; off <<= 1) {
        int u = (t >= off) ? sc[t - off] : 0;
        __syncthreads();
        sc[t] += u;
        __syncthreads();
    }
    bases[t * NB + b] = b * CAP + (sc[t] - v);
    if (t == CB - 1) bcnt[b] = sc[t];
}

// ---------------- pass 3: scatter into bucket runs (LDS cursors) --------------
__global__ __launch_bounds__(256) void bin_k(const int* __restrict__ ei,
                                             const int* __restrict__ bases,
                                             uint32_t* __restrict__ recs)
{
    __shared__ int cur[NB];
    for (int j = threadIdx.x; j < NB; j += 256)
        cur[j] = bases[blockIdx.x * NB + j];
    __syncthreads();
    const int base = blockIdx.x * EPB;
    for (int t = threadIdx.x; t < EPB; t += 256) {
        int e = base + t;
        int src = ei[e];
        int dst = ei[NE + e];
        int bkt = dst >> BSH;
        int idx = atomicAdd(&cur[bkt], 1);
        if (idx < (bkt + 1) * CAP)
            recs[idx] = ((uint32_t)(dst & 63) << 16) | (uint32_t)src;
    }
}

// ---------------- pass 4: per-bucket counting sort by dst ---------------------
__global__ __launch_bounds__(256) void sort_k(const uint32_t* __restrict__ recs,
                                              const int* __restrict__ bcnt,
                                              uint16_t* __restrict__ srt,
                                              uint32_t* __restrict__ dpack)
{
    __shared__ uint32_t sr[CAP];      // 16 KB
    __shared__ int cnt4[4][64];
    __shared__ int start64[64];
    __shared__ int cur4[4][64];
    const int b = blockIdx.x, t = threadIdx.x, w = t >> 6;
    const int n = min(bcnt[b], CAP);

    for (int j = t; j < n; j += 256) sr[j] = recs[(size_t)b * CAP + j];
    cnt4[t >> 6][t & 63] = 0;
    __syncthreads();

    for (int j = t; j < n; j += 256)
        atomicAdd(&cnt4[w][sr[j] >> 16], 1);
    __syncthreads();

    if (t == 0) {
        int acc = 0;
        #pragma unroll 8
        for (int dl = 0; dl < 64; ++dl) {
            int tot = cnt4[0][dl] + cnt4[1][dl] + cnt4[2][dl] + cnt4[3][dl];
            start64[dl] = acc;
            acc += (tot + 7) & ~7;               // 8-pad each run (uint4 loads)
        }
    }
    __syncthreads();

    if (t < 64) {
        int s = start64[t];
        int c0 = cnt4[0][t], c1 = cnt4[1][t], c2 = cnt4[2][t];
        cur4[0][t] = s;
        cur4[1][t] = s + c0;
        cur4[2][t] = s + c0 + c1;
        cur4[3][t] = s + c0 + c1 + c2;
        int dst = b * 64 + t;
        if (dst < NN) {
            int tot = c0 + c1 + c2 + cnt4[3][t];
            dpack[dst] = ((uint32_t)min(tot, 255) << 24) |
                         (uint32_t)(b * CAP + s);
        }
    }
    __syncthreads();

    for (int j = t; j < n; j += 256) {
        uint32_t r = sr[j];
        int dl = r >> 16;
        int idx = atomicAdd(&cur4[w][dl], 1);
        if (idx < CAP) srt[(size_t)b * CAP + idx] = (uint16_t)(r & 0xFFFF);
    }
}

// ---------------- fused: gemm[r] (role 0) || agg[r-1] (roles 1,2) -------------
// gemm: two-pass A staging (48 KB total LDS) -> 3 blocks/CU so agg keeps
// gather concurrency. agg: round-12 proven one-wave-per-dst CSR walk.
__global__ __launch_bounds__(256) void fused_k(
    // gemm (relation r):
    const float* __restrict__ x,  const float* __restrict__ pm,
    const float* __restrict__ nm, const float* __restrict__ Wr,
    const uint32_t* __restrict__ dpack_w, const int* __restrict__ invp_r,
    uint32_t* __restrict__ pk_w,
    // agg (relation r-1):
    const uint32_t* __restrict__ dpack_a, const uint16_t* __restrict__ srt_a,
    const uint32_t* __restrict__ pk_a, const float* __restrict__ br_a,
    float* __restrict__ outp_a, float* __restrict__ outn_a,
    float* __restrict__ summ_a,
    int do_fwd, int do_agg)
{
    __shared__ float sW[FIN * FOUT];   // 32 KB (gemm W; agg reuses as reduce buf)
    __shared__ float sA[ROWS * FIN];   // 16 KB (single buffer, two passes)
    const int t = threadIdx.x;
    const int role = blockIdx.x % 3;
    const int grp  = blockIdx.x / 3;

    if (role == 0) {
        // ---------------- gemm role ----------------
        if (!do_fwd) return;
        const int row0 = grp * ROWS;

        for (int i = t * 4; i < FIN * FOUT; i += 1024)
            *(float4*)&sW[i] = *(const float4*)&Wr[i];

        const int tr = (t >> 4) * 2;
        const int tc = (t & 15) * 4;
        float accp[2][4] = {{0.f,0.f,0.f,0.f},{0.f,0.f,0.f,0.f}};
        float accn[2][4] = {{0.f,0.f,0.f,0.f},{0.f,0.f,0.f,0.f}};

#define GEMM_PASS(MASKPTR, ACC)                                                 \
        {                                                                       \
            __syncthreads();                                                    \
            for (int i = t * 4; i < ROWS * FIN; i += 1024) {                    \
                int rr = i >> 7, cc = i & 127;                                  \
                int row = row0 + rr;                                            \
                float4 av = make_float4(0.f, 0.f, 0.f, 0.f);                    \
                if (row < NN) {                                                 \
                    size_t g = (size_t)row * FIN + cc;                          \
                    float4 xv = *(const float4*)(x + g);                        \
                    float4 mv = *(const float4*)(MASKPTR + g);                  \
                    av = make_float4(xv.x*mv.x, xv.y*mv.y, xv.z*mv.z, xv.w*mv.w);\
                }                                                               \
                *(float4*)&sA[(rr << 7) + (cc ^ ((rr & 7) << 2))] = av;         \
            }                                                                   \
            __syncthreads();                                                    \
            _Pragma("unroll 4")                                                 \
            for (int k = 0; k < FIN; k += 4) {                                  \
                float4 a0 = *(const float4*)&sA[((tr    ) << 7) + (k ^ (((tr    ) & 7) << 2))]; \
                float4 a1 = *(const float4*)&sA[((tr + 1) << 7) + (k ^ (((tr + 1) & 7) << 2))]; \
                float v0[4] = {a0.x, a0.y, a0.z, a0.w};                         \
                float v1[4] = {a1.x, a1.y, a1.z, a1.w};                         \
                _Pragma("unroll")                                               \
                for (int j = 0; j < 4; ++j) {                                   \
                    float4 wv = *(const float4*)&sW[(k + j) * FOUT + tc];       \
                    float wj[4] = {wv.x, wv.y, wv.z, wv.w};                     \
                    _Pragma("unroll")                                           \
                    for (int c = 0; c < 4; ++c) {                               \
                        ACC[0][c] += v0[j] * wj[c];                             \
                        ACC[1][c] += v1[j] * wj[c];                             \
                    }                                                           \
                }                                                               \
            }                                                                   \
        }

        GEMM_PASS(pm, accp)
        GEMM_PASS(nm, accn)
#undef GEMM_PASS

        #pragma unroll
        for (int rr = 0; rr < 2; ++rr) {
            int row = row0 + tr + rr;
            if (row >= NN) continue;
            float dp = rsqrtf((float)(dpack_w[row] >> 24) + 1.0f);
            int ni = invp_r[row];
            float dn = rsqrtf((float)(dpack_w[ni] >> 24) + 1.0f);
            #pragma unroll
            for (int c = 0; c < 4; ++c) {
                ((uint16_t*)&pk_w[(size_t)row * 64 + tc + c])[1] = (uint16_t)f2bf(accp[rr][c] * dp);
                ((uint16_t*)&pk_w[(size_t)ni  * 64 + tc + c])[0] = (uint16_t)f2bf(accn[rr][c] * dn);
            }
        }
        return;
    }

    // ---------------- agg role (relation r-1) ----------------
    if (!do_agg) return;
    int ab = grp * 2 + (role - 1);
    if (ab >= AGG_BLOCKS) return;

    const int lane = threadIdx.x & 63;
    const int w0 = ab * 4 + (threadIdx.x >> 6);
    const float bl = br_a[lane];
    float part = 0.f;

    for (int dst = w0; dst < NN; dst += 4 * AGG_BLOCKS) {
        uint32_t pc = dpack_a[dst];
        int deg = (int)(pc >> 24);
        const uint16_t* row = srt_a + (pc & 0xFFFFFFu);
        uint32_t gs = pk_a[(size_t)dst * 64 + lane];          // self-loop (scaled)
        float accp = __uint_as_float(gs & 0xFFFF0000u);
        float accn = __uint_as_float(gs << 16);
        int j = 0;
        for (; j + 8 <= deg; j += 8) {
            uint4 rv = *(const uint4*)(row + j);
            int s0 = rv.x & 0xFFFF, s1 = (int)(rv.x >> 16);
            int s2 = rv.y & 0xFFFF, s3 = (int)(rv.y >> 16);
            int s4 = rv.z & 0xFFFF, s5 = (int)(rv.z >> 16);
            int s6 = rv.w & 0xFFFF, s7 = (int)(rv.w >> 16);
            uint32_t g0 = pk_a[(size_t)s0*64+lane], g1 = pk_a[(size_t)s1*64+lane];
            uint32_t g2 = pk_a[(size_t)s2*64+lane], g3 = pk_a[(size_t)s3*64+lane];
            uint32_t g4 = pk_a[(size_t)s4*64+lane], g5 = pk_a[(size_t)s5*64+lane];
            uint32_t g6 = pk_a[(size_t)s6*64+lane], g7 = pk_a[(size_t)s7*64+lane];
            accp += __uint_as_float(g0 & 0xFFFF0000u) + __uint_as_float(g1 & 0xFFFF0000u)
                  + __uint_as_float(g2 & 0xFFFF0000u) + __uint_as_float(g3 & 0xFFFF0000u)
                  + __uint_as_float(g4 & 0xFFFF0000u) + __uint_as_float(g5 & 0xFFFF0000u)
                  + __uint_as_float(g6 & 0xFFFF0000u) + __uint_as_float(g7 & 0xFFFF0000u);
            accn += __uint_as_float(g0 << 16) + __uint_as_float(g1 << 16)
                  + __uint_as_float(g2 << 16) + __uint_as_float(g3 << 16)
                  + __uint_as_float(g4 << 16) + __uint_as_float(g5 << 16)
                  + __uint_as_float(g6 << 16) + __uint_as_float(g7 << 16);
        }
        for (; j < deg; ++j) {
            uint32_t g = pk_a[(size_t)row[j] * 64 + lane];
            accp += __uint_as_float(g & 0xFFFF0000u);
            accn += __uint_as_float(g << 16);
        }
        float d = rsqrtf((float)deg + 1.0f);
        float op = fmaxf(fmaf(d, accp, bl), 0.f);
        float on = fmaxf(fmaf(d, accn, bl), 0.f);
        outp_a[(size_t)dst * FOUT + lane] = op;
        outn_a[(size_t)dst * FOUT + lane] = on;
        part += op;
    }

    sW[t] = part;                                   // reuse sW as reduce buffer
    __syncthreads();
    if (t < 64) {
        float s = sW[t] + sW[t + 64] + sW[t + 128] + sW[t + 192];
        atomicAdd(&summ_a[t], s * (1.0f / NN));
    }
}

extern "C" void kernel_launch(void* const* d_in, const int* in_sizes, int n_in,
                              void* d_out, int out_size, void* d_ws, size_t ws_size,
                              hipStream_t stream)
{
    const float* x    = (const float*)d_in[0];
    const int*   ei   = (const int*)  d_in[1];
    const float* W    = (const float*)d_in[2];
    const float* b    = (const float*)d_in[3];
    const float* pm   = (const float*)d_in[4];
    const float* nm   = (const float*)d_in[5];
    const int*   perm = (const int*)  d_in[6];
    float* out = (float*)d_out;

    // ws: invp[R*N] | counts[CB*NB] | bases[CB*NB] | bcnt[800] | srt[2][NB*CAP] u16
    //   | dpack[2][NN] u32 | pk[2][NN*64] u32    (~40.4 MB; recs aliases pk[r&1])
    int*      invp   = (int*)d_ws;
    int*      counts = invp + (size_t)NR * NN;
    int*      bases  = counts + (size_t)CB * NB;
    int*      bcnt   = bases + (size_t)CB * NB;
    uint16_t* srt0   = (uint16_t*)(bcnt + 800);
    uint16_t* srt1   = srt0 + (size_t)NB * CAP;
    uint32_t* dpack0 = (uint32_t*)(srt1 + (size_t)NB * CAP);
    uint32_t* dpack1 = dpack0 + NN;
    uint32_t* pk0    = dpack1 + NN;
    uint32_t* pk1    = pk0 + (size_t)NN * 64;
    uint16_t* srts[2]   = {srt0, srt1};
    uint32_t* dpacks[2] = {dpack0, dpack1};
    uint32_t* pks[2]    = {pk0, pk1};

    const size_t NF = (size_t)NN * FOUT;
    float* outp0 = out;
    float* outn0 = out + (size_t)NR * NF;
    float* summ  = out + 2 * (size_t)NR * NF;

    init_k<<<dim3((NN + 255) / 256, NR), 256, 0, stream>>>(perm, invp, summ);

    for (int i = 0; i <= NR; ++i) {
        if (i < NR) {
            const int* ei_r = ei + (size_t)i * 2 * NE;
            uint32_t* recs = pks[i & 1];         // dead region during constr(i)
            cnt_k <<<dim3(CB), 256, 0, stream>>>(ei_r + NE, counts);
            scan_k<<<dim3(NB), 128, 0, stream>>>(counts, bases, bcnt);
            bin_k <<<dim3(CB), 256, 0, stream>>>(ei_r, bases, recs);
            sort_k<<<dim3(NB), 256, 0, stream>>>(recs, bcnt, srts[i & 1], dpacks[i & 1]);
        }
        int rf = (i < NR) ? i : 0;               // gemm relation (clamped)
        int ra = (i >= 1) ? (i - 1) : 0;         // agg relation (clamped)
        fused_k<<<dim3(FUSE_BLOCKS), 256, 0, stream>>>(
            x, pm + (size_t)rf * NN * FIN, nm + (size_t)rf * NN * FIN,
            W + (size_t)rf * FIN * FOUT, dpacks[rf & 1], invp + (size_t)rf * NN,
            pks[rf & 1],
            dpacks[ra & 1], srts[ra & 1], pks[ra & 1],
            b + (size_t)ra * FOUT, outp0 + (size_t)ra * NF,
            outn0 + (size_t)ra * NF, summ + (size_t)ra * FOUT,
            (i < NR) ? 1 : 0, (i >= 1) ? 1 : 0);
    }
}